// Round 3
// baseline (4453.943 us; speedup 1.0000x reference)
//
#include <hip/hip_runtime.h>
#include <hip/hip_bf16.h>

#define Nn 50000
#define Ee 1600000
#define Ff 64
#define Rr 5
#define Bb 4
#define Ll 4
#define Kk 2048
#define Mseg (Rr*Nn)   // 250000 segments, rel-major: seg = r*Nn + dst

__global__ __launch_bounds__(256) void k_inv_init(int* __restrict__ inv){
  int i = blockIdx.x*256+threadIdx.x;
  if (i < Nn) inv[i] = -1;
}

__global__ __launch_bounds__(256) void k_inv_set(const int* __restrict__ tidx, int* __restrict__ inv){
  int k = blockIdx.x*256+threadIdx.x;
  if (k < Kk) inv[tidx[k]] = k;
}

__global__ __launch_bounds__(256) void k_cnt2(const int* __restrict__ ei, const int* __restrict__ et,
                                              int* __restrict__ cnt2){
  int e = blockIdx.x*256+threadIdx.x;
  if (e < Ee){
    int dst = ei[Ee + e];
    int r = et[e];
    atomicAdd(&cnt2[r*Nn + dst], 1);
  }
}

// exclusive scan, stage 1: per-256-block scan + block sums
__global__ __launch_bounds__(256) void k_scan_blk(const int* __restrict__ cnt2, int* __restrict__ part,
                                                  int* __restrict__ bsum){
  __shared__ int s[256];
  int t = threadIdx.x; int idx = blockIdx.x*256+t;
  int v = (idx < Mseg) ? cnt2[idx] : 0;
  s[t] = v; __syncthreads();
  #pragma unroll
  for (int off=1; off<256; off<<=1){
    int x = (t>=off) ? s[t-off] : 0;
    __syncthreads();
    s[t] += x;
    __syncthreads();
  }
  if (idx < Mseg) part[idx] = s[t] - v;      // exclusive within block
  if (t == 255) bsum[blockIdx.x] = s[255];
}

// stage 2: scan the (<=1024) block sums in one block, in place -> exclusive
__global__ __launch_bounds__(1024) void k_scan_top(int* __restrict__ bsum, int nb){
  __shared__ int s[1024];
  int t = threadIdx.x;
  int v = (t < nb) ? bsum[t] : 0;
  s[t] = v; __syncthreads();
  #pragma unroll
  for (int off=1; off<1024; off<<=1){
    int x = (t>=off) ? s[t-off] : 0;
    __syncthreads();
    s[t] += x;
    __syncthreads();
  }
  if (t < nb) bsum[t] = s[t] - v;
}

// stage 3: combine -> rowptr (exclusive), plus sentinel rowptr[Mseg]=E
__global__ __launch_bounds__(256) void k_scan_add(const int* __restrict__ part, const int* __restrict__ bsum,
                                                  int* __restrict__ rowptr){
  int idx = blockIdx.x*256+threadIdx.x;
  if (idx < Mseg) rowptr[idx] = part[idx] + bsum[idx>>8];
  if (idx == 0) rowptr[Mseg] = Ee;
}

// place edges: edg[pos] = src | dst<<16  (both < 65536)
__global__ __launch_bounds__(256) void k_place(const int* __restrict__ ei, const int* __restrict__ et,
                                               const int* __restrict__ rowptr, int* __restrict__ fill,
                                               unsigned* __restrict__ edg){
  int e = blockIdx.x*256+threadIdx.x;
  if (e < Ee){
    int src = ei[e];
    int dst = ei[Ee + e];
    int r = et[e];
    int seg = r*Nn + dst;
    int pos = rowptr[seg] + atomicAdd(&fill[seg], 1);
    edg[pos] = (unsigned)src | ((unsigned)dst << 16);
  }
}

// Wall: 384x64 fp32. rows 0..319 = W_r, rows 320..383 = root.
__global__ __launch_bounds__(256) void k_wall(const float* __restrict__ bases, const float* __restrict__ comps,
                                              const float* __restrict__ roots, float* __restrict__ Wall){
  int idx = blockIdx.x*256+threadIdx.x;
  if (idx >= 384*64) return;
  int o = idx & 63, row = idx >> 6;
  float s;
  if (row < 320){
    int r = row >> 6, i = row & 63;
    s = 0.f;
    #pragma unroll
    for (int b=0;b<Bb;b++)
      s += comps[r*Bb+b] * bases[(b*Ff + i)*Ff + o];
  } else {
    int i = row - 320;
    s = roots[i*Ff + o];
  }
  Wall[idx] = s;
}

#define SVP 68   // padded LDS row stride (floats): 2-way bank alias only, 16B aligned

// Fused RGCN layer: per block = 64 nodes x 64 outputs.
// For each rel c: gather edge rows into LDS (ds_add_f32), mean-divide, then
// register-blocked (4 nodes x 4 outs per thread) matmul with W_c from LDS.
__global__ __launch_bounds__(256) void k_rgcn(const unsigned* __restrict__ edg, const int* __restrict__ rowptr,
    const float* __restrict__ Wall, const float* __restrict__ h, const float* __restrict__ bias,
    float* __restrict__ hn, const int* __restrict__ inv, float* __restrict__ sel, int layer)
{
  __shared__ __align__(16) float sW[64*64];
  __shared__ __align__(16) float sV[64*SVP];
  int t = threadIdx.x;
  int n0 = blockIdx.x*64;
  int nlim = Nn - n0; if (nlim > 64) nlim = 64;
  int w = t >> 6, f = t & 63;
  int oq = (t & 15)*4, nq = (t >> 4)*4;
  float4 acc[4];
  #pragma unroll
  for (int j=0;j<4;j++) acc[j] = make_float4(0.f,0.f,0.f,0.f);

  for (int c=0;c<6;c++){
    // stage W_c (prev iteration ended with a barrier)
    for (int idx=t; idx<4096; idx+=256) sW[idx] = Wall[c*4096+idx];
    if (c < 5){
      for (int idx=t; idx<4096; idx+=256) sV[(idx>>6)*SVP + (idx&63)] = 0.f;
      __syncthreads();
      int segbase = c*Nn + n0;
      int s = rowptr[segbase];
      int e = rowptr[segbase + nlim];
      for (int i = s + w; i < e; i += 4){
        unsigned u = edg[i];
        int src = (int)(u & 0xffffu);
        int dst = (int)(u >> 16);
        float v = h[src*64 + f];
        atomicAdd(&sV[(dst - n0)*SVP + f], v);
      }
      __syncthreads();
      // mean divide by segment length
      for (int idx=t; idx<4096; idx+=256){
        int nl = idx>>6, i = idx&63;
        if (nl < nlim){
          int cc = rowptr[segbase+nl+1] - rowptr[segbase+nl];
          if (cc > 1) sV[nl*SVP+i] *= (1.0f/(float)cc);
        }
      }
      __syncthreads();
    } else {
      // root term: sV = h rows
      for (int idx=t; idx<4096; idx+=256){
        int nl = idx>>6, i = idx&63;
        sV[nl*SVP+i] = (nl < nlim) ? h[(n0+nl)*64 + i] : 0.f;
      }
      __syncthreads();
    }
    // register-blocked matmul: acc[j][o'] += sum_i sV[nq+j][i] * sW[i][oq+o']
    #pragma unroll
    for (int i=0;i<64;i+=4){
      float4 v0 = *(const float4*)&sV[(nq+0)*SVP + i];
      float4 v1 = *(const float4*)&sV[(nq+1)*SVP + i];
      float4 v2 = *(const float4*)&sV[(nq+2)*SVP + i];
      float4 v3 = *(const float4*)&sV[(nq+3)*SVP + i];
      float4 w0 = *(const float4*)&sW[(i+0)*64 + oq];
      float4 w1 = *(const float4*)&sW[(i+1)*64 + oq];
      float4 w2 = *(const float4*)&sW[(i+2)*64 + oq];
      float4 w3 = *(const float4*)&sW[(i+3)*64 + oq];
      #define FMA4(A, V) \
        A.x += V.x*w0.x + V.y*w1.x + V.z*w2.x + V.w*w3.x; \
        A.y += V.x*w0.y + V.y*w1.y + V.z*w2.y + V.w*w3.y; \
        A.z += V.x*w0.z + V.y*w1.z + V.z*w2.z + V.w*w3.z; \
        A.w += V.x*w0.w + V.y*w1.w + V.z*w2.w + V.w*w3.w;
      FMA4(acc[0], v0)
      FMA4(acc[1], v1)
      FMA4(acc[2], v2)
      FMA4(acc[3], v3)
      #undef FMA4
    }
    __syncthreads();
  }

  float4 bb = *(const float4*)&bias[oq];
  #pragma unroll
  for (int j=0;j<4;j++){
    int n = n0 + nq + j;
    if (n < Nn){
      float4 r;
      r.x = tanhf(acc[j].x + bb.x);
      r.y = tanhf(acc[j].y + bb.y);
      r.z = tanhf(acc[j].z + bb.z);
      r.w = tanhf(acc[j].w + bb.w);
      *(float4*)&hn[n*64 + oq] = r;
      int k = inv[n];
      if (k >= 0) *(float4*)&sel[(size_t)k*256 + layer*64 + oq] = r;
    }
  }
}

__global__ __launch_bounds__(256) void k_w1eff(const float* __restrict__ w1, float* __restrict__ w1e){
  int idx = blockIdx.x*256+threadIdx.x;
  if (idx < 256*128){
    int i = idx >> 7, j = idx & 127;
    w1e[idx] = w1[i*128 + j] + w1[(i+256)*128 + j];
  }
}

__global__ __launch_bounds__(128) void k_mlp(const float* __restrict__ sel, const float* __restrict__ w1e,
    const float* __restrict__ b1, const float* __restrict__ w2, const float* __restrict__ b2,
    float* __restrict__ out)
{
  __shared__ float sfeat[256];
  __shared__ float partial[2];
  int k = blockIdx.x, j = threadIdx.x;   // 128 threads = 2 waves
  for (int idx=j; idx<256; idx+=128) sfeat[idx] = sel[(size_t)k*256 + idx];
  __syncthreads();
  float a = b1[j];
  for (int i=0;i<256;i++) a += sfeat[i] * w1e[i*128 + j];
  a = fmaxf(a, 0.f);
  float v = a * w2[j];
  #pragma unroll
  for (int off=32; off>0; off>>=1) v += __shfl_down(v, off, 64);
  if ((j & 63) == 0) partial[j>>6] = v;
  __syncthreads();
  if (j == 0) out[k] = partial[0] + partial[1] + b2[0];
}

extern "C" void kernel_launch(void* const* d_in, const int* in_sizes, int n_in,
                              void* d_out, int out_size, void* d_ws, size_t ws_size,
                              hipStream_t stream){
  const float* x     = (const float*)d_in[0];
  const int*  ei     = (const int*)d_in[1];   // [2,E]: [0..E)=src, [E..2E)=dst
  const int*  et     = (const int*)d_in[2];
  const int*  tidx   = (const int*)d_in[3];
  const float* bases = (const float*)d_in[4]; // [L,B,F,F]
  const float* comps = (const float*)d_in[5]; // [L,R,B]
  const float* roots = (const float*)d_in[6]; // [L,F,F]
  const float* biases= (const float*)d_in[7]; // [L,F]
  const float* w1    = (const float*)d_in[8]; // [512,128]
  const float* b1    = (const float*)d_in[9]; // [128]
  const float* w2    = (const float*)d_in[10];// [128,1]
  const float* b2    = (const float*)d_in[11];// [1]
  float* out = (float*)d_out;

  char* wsp = (char*)d_ws;
  size_t off = 0;
  auto alloc = [&](size_t bytes)->void*{ void* p = wsp + off; off += (bytes + 255) & ~size_t(255); return p; };
  float*    h0    = (float*)alloc(sizeof(float)*(size_t)Nn*Ff);
  float*    h1    = (float*)alloc(sizeof(float)*(size_t)Nn*Ff);
  int*      cnt2  = (int*)  alloc(sizeof(int)*(Mseg));
  int*      part  = (int*)  alloc(sizeof(int)*(Mseg));
  int*      bsum  = (int*)  alloc(sizeof(int)*1024);
  int*      rowptr= (int*)  alloc(sizeof(int)*(Mseg+1));
  int*      fill  = (int*)  alloc(sizeof(int)*(Mseg));
  unsigned* edg   = (unsigned*)alloc(sizeof(unsigned)*(size_t)Ee);
  float*    Wall  = (float*)alloc(sizeof(float)*384*64);
  float*    sel   = (float*)alloc(sizeof(float)*(size_t)Kk*256);
  float*    w1e   = (float*)alloc(sizeof(float)*256*128);
  int*      inv   = (int*)  alloc(sizeof(int)*(size_t)Nn);
  (void)ws_size;

  const int NB = (Mseg + 255)/256;   // 977 scan blocks

  hipMemsetAsync(cnt2, 0, sizeof(int)*Mseg, stream);
  hipMemsetAsync(fill, 0, sizeof(int)*Mseg, stream);
  k_inv_init<<<(Nn+255)/256, 256, 0, stream>>>(inv);
  k_inv_set<<<(Kk+255)/256, 256, 0, stream>>>(tidx, inv);
  k_w1eff<<<(256*128+255)/256, 256, 0, stream>>>(w1, w1e);
  k_cnt2<<<(Ee+255)/256, 256, 0, stream>>>(ei, et, cnt2);
  k_scan_blk<<<NB, 256, 0, stream>>>(cnt2, part, bsum);
  k_scan_top<<<1, 1024, 0, stream>>>(bsum, NB);
  k_scan_add<<<NB, 256, 0, stream>>>(part, bsum, rowptr);
  k_place<<<(Ee+255)/256, 256, 0, stream>>>(ei, et, rowptr, fill, edg);

  const float* hc = x;
  float* hn = h0;
  for (int l=0;l<Ll;l++){
    k_wall<<<(384*64+255)/256, 256, 0, stream>>>(bases + (size_t)l*Bb*Ff*Ff, comps + (size_t)l*Rr*Bb,
                                                 roots + (size_t)l*Ff*Ff, Wall);
    k_rgcn<<<(Nn+63)/64, 256, 0, stream>>>(edg, rowptr, Wall, hc, biases + (size_t)l*Ff, hn, inv, sel, l);
    hc = hn;
    hn = (hn == h0) ? h1 : h0;
  }
  k_mlp<<<Kk, 128, 0, stream>>>(sel, w1e, b1, w2, b2, out);
}

// Round 4
// 1128.876 us; speedup vs baseline: 3.9455x; 3.9455x over previous
//
#include <hip/hip_runtime.h>
#include <hip/hip_bf16.h>

#define Nn 50000
#define Ee 1600000
#define Ff 64
#define Rr 5
#define Bb 4
#define Ll 4
#define Kk 2048
#define Mseg (Rr*Nn)   // 250000 segments, rel-major: seg = r*Nn + dst

__global__ __launch_bounds__(256) void k_inv_init(int* __restrict__ inv){
  int i = blockIdx.x*256+threadIdx.x;
  if (i < Nn) inv[i] = -1;
}

__global__ __launch_bounds__(256) void k_inv_set(const int* __restrict__ tidx, int* __restrict__ inv){
  int k = blockIdx.x*256+threadIdx.x;
  if (k < Kk) inv[tidx[k]] = k;
}

__global__ __launch_bounds__(256) void k_cnt2(const int* __restrict__ ei, const int* __restrict__ et,
                                              int* __restrict__ cnt2){
  int e = blockIdx.x*256+threadIdx.x;
  if (e < Ee){
    int dst = ei[Ee + e];
    int r = et[e];
    atomicAdd(&cnt2[r*Nn + dst], 1);
  }
}

// exclusive scan, stage 1: per-256-block scan + block sums
__global__ __launch_bounds__(256) void k_scan_blk(const int* __restrict__ cnt2, int* __restrict__ part,
                                                  int* __restrict__ bsum){
  __shared__ int s[256];
  int t = threadIdx.x; int idx = blockIdx.x*256+t;
  int v = (idx < Mseg) ? cnt2[idx] : 0;
  s[t] = v; __syncthreads();
  #pragma unroll
  for (int off=1; off<256; off<<=1){
    int x = (t>=off) ? s[t-off] : 0;
    __syncthreads();
    s[t] += x;
    __syncthreads();
  }
  if (idx < Mseg) part[idx] = s[t] - v;      // exclusive within block
  if (t == 255) bsum[blockIdx.x] = s[255];
}

// stage 2: scan the (<=1024) block sums in one block, in place -> exclusive
__global__ __launch_bounds__(1024) void k_scan_top(int* __restrict__ bsum, int nb){
  __shared__ int s[1024];
  int t = threadIdx.x;
  int v = (t < nb) ? bsum[t] : 0;
  s[t] = v; __syncthreads();
  #pragma unroll
  for (int off=1; off<1024; off<<=1){
    int x = (t>=off) ? s[t-off] : 0;
    __syncthreads();
    s[t] += x;
    __syncthreads();
  }
  if (t < nb) bsum[t] = s[t] - v;
}

// stage 3: combine -> rowptr (exclusive), plus sentinel rowptr[Mseg]=E
__global__ __launch_bounds__(256) void k_scan_add(const int* __restrict__ part, const int* __restrict__ bsum,
                                                  int* __restrict__ rowptr){
  int idx = blockIdx.x*256+threadIdx.x;
  if (idx < Mseg) rowptr[idx] = part[idx] + bsum[idx>>8];
  if (idx == 0) rowptr[Mseg] = Ee;
}

// place edges into CSR (by seg), storing only src as u16 (src < 50000 < 65536)
__global__ __launch_bounds__(256) void k_place(const int* __restrict__ ei, const int* __restrict__ et,
                                               const int* __restrict__ rowptr, int* __restrict__ fill,
                                               unsigned short* __restrict__ srcs){
  int e = blockIdx.x*256+threadIdx.x;
  if (e < Ee){
    int src = ei[e];
    int dst = ei[Ee + e];
    int r = et[e];
    int seg = r*Nn + dst;
    int pos = rowptr[seg] + atomicAdd(&fill[seg], 1);
    srcs[pos] = (unsigned short)src;
  }
}

// Wall: 384x64 fp32. rows 0..319 = W_r, rows 320..383 = root.
__global__ __launch_bounds__(256) void k_wall(const float* __restrict__ bases, const float* __restrict__ comps,
                                              const float* __restrict__ roots, float* __restrict__ Wall){
  int idx = blockIdx.x*256+threadIdx.x;
  if (idx >= 384*64) return;
  int o = idx & 63, row = idx >> 6;
  float s;
  if (row < 320){
    int r = row >> 6, i = row & 63;
    s = 0.f;
    #pragma unroll
    for (int b=0;b<Bb;b++)
      s += comps[r*Bb+b] * bases[(b*Ff + i)*Ff + o];
  } else {
    int i = row - 320;
    s = roots[i*Ff + o];
  }
  Wall[idx] = s;
}

// Segment mean: one wave per segment. lane = feature. Edges CSR-contiguous;
// 4-unrolled independent row gathers, register accumulate, coalesced y write.
__global__ __launch_bounds__(256) void k_seg(const unsigned short* __restrict__ srcs,
                                             const int* __restrict__ rowptr,
                                             const float* __restrict__ h, float* __restrict__ y){
  int seg = blockIdx.x*4 + (threadIdx.x >> 6);
  if (seg >= Mseg) return;
  int f = threadIdx.x & 63;
  int s = rowptr[seg], e = rowptr[seg+1];
  float acc = 0.f;
  int i = s;
  for (; i+4 <= e; i+=4){
    int s0 = srcs[i+0], s1 = srcs[i+1], s2 = srcs[i+2], s3 = srcs[i+3];
    float v0 = h[s0*64+f];
    float v1 = h[s1*64+f];
    float v2 = h[s2*64+f];
    float v3 = h[s3*64+f];
    acc += (v0+v1) + (v2+v3);
  }
  for (; i<e; i++) acc += h[srcs[i]*64+f];
  int cc = e - s;
  y[(size_t)seg*64 + f] = (cc>0) ? acc * (1.0f/(float)cc) : 0.f;
}

#define SVP 68   // padded LDS row stride (floats): 2-way bank alias only, 16B aligned

// Combine: per block = 64 nodes x 64 outputs. For c<5 stage y tile, c=5 stage h tile;
// register-blocked 4x4 matmul vs W_c; epilogue bias+tanh, write hn (+sel rows).
__global__ __launch_bounds__(256) void k_comb2(const float* __restrict__ y, const float* __restrict__ h,
    const float* __restrict__ Wall, const float* __restrict__ bias,
    float* __restrict__ hn, const int* __restrict__ inv, float* __restrict__ sel, int layer)
{
  __shared__ __align__(16) float sW[64*64];
  __shared__ __align__(16) float sV[64*SVP];
  int t = threadIdx.x;
  int n0 = blockIdx.x*64;
  int nlim = Nn - n0; if (nlim > 64) nlim = 64;
  int oq = (t & 15)*4, nq = (t >> 4)*4;
  float4 acc[4];
  #pragma unroll
  for (int j=0;j<4;j++) acc[j] = make_float4(0.f,0.f,0.f,0.f);

  for (int c=0;c<6;c++){
    #pragma unroll
    for (int idx=t; idx<1024; idx+=256){
      *(float4*)&sW[idx*4] = *(const float4*)&Wall[c*4096 + idx*4];
      int nl = idx>>4, iq = (idx&15)*4;
      float4 v = make_float4(0.f,0.f,0.f,0.f);
      if (nl < nlim){
        if (c < 5) v = *(const float4*)&y[((size_t)(c*Nn + n0 + nl))*64 + iq];
        else       v = *(const float4*)&h[(size_t)(n0 + nl)*64 + iq];
      }
      *(float4*)&sV[nl*SVP + iq] = v;
    }
    __syncthreads();
    #pragma unroll
    for (int i=0;i<64;i+=4){
      float4 v0 = *(const float4*)&sV[(nq+0)*SVP + i];
      float4 v1 = *(const float4*)&sV[(nq+1)*SVP + i];
      float4 v2 = *(const float4*)&sV[(nq+2)*SVP + i];
      float4 v3 = *(const float4*)&sV[(nq+3)*SVP + i];
      float4 w0 = *(const float4*)&sW[(i+0)*64 + oq];
      float4 w1 = *(const float4*)&sW[(i+1)*64 + oq];
      float4 w2 = *(const float4*)&sW[(i+2)*64 + oq];
      float4 w3 = *(const float4*)&sW[(i+3)*64 + oq];
      #define FMA4(A, V) \
        A.x += V.x*w0.x + V.y*w1.x + V.z*w2.x + V.w*w3.x; \
        A.y += V.x*w0.y + V.y*w1.y + V.z*w2.y + V.w*w3.y; \
        A.z += V.x*w0.z + V.y*w1.z + V.z*w2.z + V.w*w3.z; \
        A.w += V.x*w0.w + V.y*w1.w + V.z*w2.w + V.w*w3.w;
      FMA4(acc[0], v0)
      FMA4(acc[1], v1)
      FMA4(acc[2], v2)
      FMA4(acc[3], v3)
      #undef FMA4
    }
    __syncthreads();
  }

  float4 bb = *(const float4*)&bias[oq];
  #pragma unroll
  for (int j=0;j<4;j++){
    int n = n0 + nq + j;
    if (n < Nn){
      float4 r;
      r.x = tanhf(acc[j].x + bb.x);
      r.y = tanhf(acc[j].y + bb.y);
      r.z = tanhf(acc[j].z + bb.z);
      r.w = tanhf(acc[j].w + bb.w);
      *(float4*)&hn[n*64 + oq] = r;
      int k = inv[n];
      if (k >= 0) *(float4*)&sel[(size_t)k*256 + layer*64 + oq] = r;
    }
  }
}

__global__ __launch_bounds__(256) void k_w1eff(const float* __restrict__ w1, float* __restrict__ w1e){
  int idx = blockIdx.x*256+threadIdx.x;
  if (idx < 256*128){
    int i = idx >> 7, j = idx & 127;
    w1e[idx] = w1[i*128 + j] + w1[(i+256)*128 + j];
  }
}

__global__ __launch_bounds__(128) void k_mlp(const float* __restrict__ sel, const float* __restrict__ w1e,
    const float* __restrict__ b1, const float* __restrict__ w2, const float* __restrict__ b2,
    float* __restrict__ out)
{
  __shared__ float sfeat[256];
  __shared__ float partial[2];
  int k = blockIdx.x, j = threadIdx.x;   // 128 threads = 2 waves
  for (int idx=j; idx<256; idx+=128) sfeat[idx] = sel[(size_t)k*256 + idx];
  __syncthreads();
  float a = b1[j];
  for (int i=0;i<256;i++) a += sfeat[i] * w1e[i*128 + j];
  a = fmaxf(a, 0.f);
  float v = a * w2[j];
  #pragma unroll
  for (int off=32; off>0; off>>=1) v += __shfl_down(v, off, 64);
  if ((j & 63) == 0) partial[j>>6] = v;
  __syncthreads();
  if (j == 0) out[k] = partial[0] + partial[1] + b2[0];
}

extern "C" void kernel_launch(void* const* d_in, const int* in_sizes, int n_in,
                              void* d_out, int out_size, void* d_ws, size_t ws_size,
                              hipStream_t stream){
  const float* x     = (const float*)d_in[0];
  const int*  ei     = (const int*)d_in[1];   // [2,E]: [0..E)=src, [E..2E)=dst
  const int*  et     = (const int*)d_in[2];
  const int*  tidx   = (const int*)d_in[3];
  const float* bases = (const float*)d_in[4]; // [L,B,F,F]
  const float* comps = (const float*)d_in[5]; // [L,R,B]
  const float* roots = (const float*)d_in[6]; // [L,F,F]
  const float* biases= (const float*)d_in[7]; // [L,F]
  const float* w1    = (const float*)d_in[8]; // [512,128]
  const float* b1    = (const float*)d_in[9]; // [128]
  const float* w2    = (const float*)d_in[10];// [128,1]
  const float* b2    = (const float*)d_in[11];// [1]
  float* out = (float*)d_out;

  char* wsp = (char*)d_ws;
  size_t off = 0;
  auto alloc = [&](size_t bytes)->void*{ void* p = wsp + off; off += (bytes + 255) & ~size_t(255); return p; };
  float*    h0    = (float*)alloc(sizeof(float)*(size_t)Nn*Ff);   // 12.8 MB
  float*    h1    = (float*)alloc(sizeof(float)*(size_t)Nn*Ff);   // 12.8 MB
  float*    y     = (float*)alloc(sizeof(float)*(size_t)Mseg*Ff); // 64 MB
  int*      cnt2  = (int*)  alloc(sizeof(int)*(Mseg));
  int*      part  = (int*)  alloc(sizeof(int)*(Mseg));
  int*      bsum  = (int*)  alloc(sizeof(int)*1024);
  int*      rowptr= (int*)  alloc(sizeof(int)*(Mseg+1));
  int*      fill  = (int*)  alloc(sizeof(int)*(Mseg));
  unsigned short* srcs = (unsigned short*)alloc(sizeof(unsigned short)*(size_t)Ee);
  float*    Wall  = (float*)alloc(sizeof(float)*384*64);
  float*    sel   = (float*)alloc(sizeof(float)*(size_t)Kk*256);
  float*    w1e   = (float*)alloc(sizeof(float)*256*128);
  int*      inv   = (int*)  alloc(sizeof(int)*(size_t)Nn);
  (void)ws_size;

  const int NB = (Mseg + 255)/256;   // 977 scan blocks

  hipMemsetAsync(cnt2, 0, sizeof(int)*Mseg, stream);
  hipMemsetAsync(fill, 0, sizeof(int)*Mseg, stream);
  k_inv_init<<<(Nn+255)/256, 256, 0, stream>>>(inv);
  k_inv_set<<<(Kk+255)/256, 256, 0, stream>>>(tidx, inv);
  k_w1eff<<<(256*128+255)/256, 256, 0, stream>>>(w1, w1e);
  k_cnt2<<<(Ee+255)/256, 256, 0, stream>>>(ei, et, cnt2);
  k_scan_blk<<<NB, 256, 0, stream>>>(cnt2, part, bsum);
  k_scan_top<<<1, 1024, 0, stream>>>(bsum, NB);
  k_scan_add<<<NB, 256, 0, stream>>>(part, bsum, rowptr);
  k_place<<<(Ee+255)/256, 256, 0, stream>>>(ei, et, rowptr, fill, srcs);

  const float* hc = x;
  float* hn = h0;
  for (int l=0;l<Ll;l++){
    k_wall<<<(384*64+255)/256, 256, 0, stream>>>(bases + (size_t)l*Bb*Ff*Ff, comps + (size_t)l*Rr*Bb,
                                                 roots + (size_t)l*Ff*Ff, Wall);
    k_seg<<<(Mseg+3)/4, 256, 0, stream>>>(srcs, rowptr, hc, y);
    k_comb2<<<(Nn+63)/64, 256, 0, stream>>>(y, hc, Wall, biases + (size_t)l*Ff, hn, inv, sel, l);
    hc = hn;
    hn = (hn == h0) ? h1 : h0;
  }
  k_mlp<<<Kk, 128, 0, stream>>>(sel, w1e, b1, w2, b2, out);
}